// Round 1
// baseline (825.928 us; speedup 1.0000x reference)
//
#include <hip/hip_runtime.h>

// ContinuousAxialDW: out = x + axialH(x) + axialW(x)
// x: [B=8, C=96, H=256, W=256] fp32
// weight_h: [C,1,7,1] -> taps_h[i][c] = wh[c*7+i], offset off=i-3 along H
// weight_w: [C,1,1,7] -> taps_w[i][c] = ww[c*7+i], offset off=i-3 along W
// r scalar (clamped to >=1). Sampling pos = coord + off*r, bilinear, zero pad.
//
// Since coord is integer: floor(coord + off*r) = coord + floor(off*r) and the
// bilinear frac is per-tap constant. Each continuous tap == two integer taps.
// We build per-channel integer stencils wtv[-8..8], wth[-8..8] once per thread
// (wave-uniform since c is block-uniform), then do plain stencil FMAs.

constexpr int B = 8, C = 96, H = 256, W = 256;
constexpr int KT = 7;       // taps per axis
constexpr int HALO = 8;     // supported integer-tap radius (covers r <= ~2.3)
constexpr int NW = 2 * HALO + 1;

__global__ __launch_bounds__(256) void axialdw_kernel(
    const float* __restrict__ x,
    const float* __restrict__ wh,
    const float* __restrict__ ww,
    const float* __restrict__ rp,
    float* __restrict__ out)
{
    // grid: B*C*(H/4) blocks; block = 4 waves; wave -> one row (b,c,h)
    const int hb   = blockIdx.x % (H / 4);
    const int bc   = blockIdx.x / (H / 4);
    const int c    = bc % C;
    const int wave = threadIdx.x >> 6;
    const int lane = threadIdx.x & 63;
    const int h    = hb * 4 + wave;
    const int w0   = lane * 4;

    float r = rp[0];
    if (r < 1.0f) r = 1.0f;

    // --- build combined integer-tap stencils (wave-uniform) ---
    float th[KT], tw[KT];
#pragma unroll
    for (int i = 0; i < KT; ++i) {
        th[i] = wh[c * KT + i];
        tw[i] = ww[c * KT + i];
    }

    float wtv[NW], wth[NW];
#pragma unroll
    for (int d = -HALO; d <= HALO; ++d) {
        float av = 0.f, aw = 0.f;
#pragma unroll
        for (int i = 0; i < KT; ++i) {
            float s   = (float)(i - 3) * r;   // pixel shift for this tap
            float d0f = floorf(s);
            int   d0  = (int)d0f;
            float f   = s - d0f;              // constant bilinear frac
            if (d == d0)     { av = fmaf(th[i], 1.f - f, av); aw = fmaf(tw[i], 1.f - f, aw); }
            if (d == d0 + 1) { av = fmaf(th[i], f, av);       aw = fmaf(tw[i], f, aw); }
        }
        wtv[d + HALO] = av;
        wth[d + HALO] = aw;
    }

    const float* plane = x + (size_t)bc * H * W;
    const float* row   = plane + (size_t)h * W;

    // --- stage horizontal span w0-HALO-? : 20 floats = 5 aligned float4 ---
    float span[20];
#pragma unroll
    for (int k = 0; k < 5; ++k) {
        const int wb = w0 - 8 + 4 * k;
        float4 v;
        if (wb >= 0 && wb + 3 < W) {
            v = *(const float4*)(row + wb);
        } else {
            v.x = (wb + 0 >= 0 && wb + 0 < W) ? row[wb + 0] : 0.f;
            v.y = (wb + 1 >= 0 && wb + 1 < W) ? row[wb + 1] : 0.f;
            v.z = (wb + 2 >= 0 && wb + 2 < W) ? row[wb + 2] : 0.f;
            v.w = (wb + 3 >= 0 && wb + 3 < W) ? row[wb + 3] : 0.f;
        }
        span[4 * k + 0] = v.x;
        span[4 * k + 1] = v.y;
        span[4 * k + 2] = v.z;
        span[4 * k + 3] = v.w;
    }

    // residual: x itself (span center)
    float acc0 = span[HALO + 0];
    float acc1 = span[HALO + 1];
    float acc2 = span[HALO + 2];
    float acc3 = span[HALO + 3];

    // --- horizontal stencil (static register indexing) ---
#pragma unroll
    for (int d = 0; d < NW; ++d) {
        const float wg = wth[d];
        acc0 = fmaf(wg, span[d + 0], acc0);
        acc1 = fmaf(wg, span[d + 1], acc1);
        acc2 = fmaf(wg, span[d + 2], acc2);
        acc3 = fmaf(wg, span[d + 3], acc3);
    }

    // --- vertical stencil (coalesced float4 row loads, uniform skip) ---
#pragma unroll
    for (int d = 0; d < NW; ++d) {
        const float wg = wtv[d];
        const int hh = h + d - HALO;
        if (wg != 0.f && hh >= 0 && hh < H) {
            const float4 v = *(const float4*)(plane + (size_t)hh * W + w0);
            acc0 = fmaf(wg, v.x, acc0);
            acc1 = fmaf(wg, v.y, acc1);
            acc2 = fmaf(wg, v.z, acc2);
            acc3 = fmaf(wg, v.w, acc3);
        }
    }

    float4 o;
    o.x = acc0; o.y = acc1; o.z = acc2; o.w = acc3;
    *(float4*)(out + (size_t)bc * H * W + (size_t)h * W + w0) = o;
}

extern "C" void kernel_launch(void* const* d_in, const int* in_sizes, int n_in,
                              void* d_out, int out_size, void* d_ws, size_t ws_size,
                              hipStream_t stream) {
    const float* x  = (const float*)d_in[0];
    const float* wh = (const float*)d_in[1];
    const float* ww = (const float*)d_in[2];
    const float* rp = (const float*)d_in[3];
    float* out = (float*)d_out;

    const int blocks = B * C * (H / 4);   // 49152
    axialdw_kernel<<<blocks, 256, 0, stream>>>(x, wh, ww, rp, out);
}

// Round 2
// 453.197 us; speedup vs baseline: 1.8224x; 1.8224x over previous
//
#include <hip/hip_runtime.h>

// ContinuousAxialDW: out = x + axialH(x) + axialW(x)
// x: [B=8, C=96, H=256, W=256] fp32
//
// Continuous taps collapse to integer-offset stencils (frac is per-tap
// constant). Round 1 lesson: building the 17-tap combined stencil per-thread
// was ~85% of VALU issue. Now a tiny pre-pass kernel builds per-channel
// stencils into d_ws; the main kernel loads them (block-uniform -> s_load).

constexpr int B = 8, C = 96, H = 256, W = 256;
constexpr int KT = 7;       // taps per axis
constexpr int HALO = 8;     // integer-tap radius (covers r <= ~2.3)
constexpr int NW = 2 * HALO + 1;

// d_ws layout: [0 .. C*NW)          = wtv (vertical / H-axis stencil)
//              [C*NW .. 2*C*NW)     = wth (horizontal / W-axis stencil)

__global__ __launch_bounds__(64) void build_stencils(
    const float* __restrict__ wh,
    const float* __restrict__ ww,
    const float* __restrict__ rp,
    float* __restrict__ ws)
{
    const int c = blockIdx.x;        // 0..C-1
    const int d = threadIdx.x;       // 0..63, only d < NW active
    if (d >= NW) return;

    float r = rp[0];
    if (r < 1.0f) r = 1.0f;

    float av = 0.f, aw = 0.f;
#pragma unroll
    for (int i = 0; i < KT; ++i) {
        float s   = (float)(i - 3) * r;   // pixel shift of tap i
        float d0f = floorf(s);
        int   d0  = (int)d0f;
        float f   = s - d0f;              // constant bilinear frac
        float thv = wh[c * KT + i];
        float twv = ww[c * KT + i];
        if (d - HALO == d0)     { av = fmaf(thv, 1.f - f, av); aw = fmaf(twv, 1.f - f, aw); }
        if (d - HALO == d0 + 1) { av = fmaf(thv, f, av);       aw = fmaf(twv, f, aw); }
    }
    ws[c * NW + d]          = av;
    ws[C * NW + c * NW + d] = aw;
}

__global__ __launch_bounds__(256) void axialdw_kernel(
    const float* __restrict__ x,
    const float* __restrict__ ws,
    float* __restrict__ out)
{
    // grid: B*C*(H/4) blocks; block = 4 waves; wave -> one row (b,c,h)
    const int hb   = blockIdx.x % (H / 4);
    const int bc   = blockIdx.x / (H / 4);
    const int c    = bc % C;
    const int wave = threadIdx.x >> 6;
    const int lane = threadIdx.x & 63;
    const int h    = hb * 4 + wave;
    const int w0   = lane * 4;

    // block-uniform stencil loads (compiler should emit s_load)
    float wtv[NW], wth[NW];
#pragma unroll
    for (int d = 0; d < NW; ++d) {
        wtv[d] = ws[c * NW + d];
        wth[d] = ws[C * NW + c * NW + d];
    }

    const float* plane = x + (size_t)bc * H * W;
    const float* row   = plane + (size_t)h * W;

    // --- stage horizontal span [w0-8, w0+12) : 5 aligned float4 ---
    float span[20];
#pragma unroll
    for (int k = 0; k < 5; ++k) {
        const int wb = w0 - 8 + 4 * k;
        float4 v;
        if (wb >= 0 && wb + 3 < W) {
            v = *(const float4*)(row + wb);
        } else {
            v.x = (wb + 0 >= 0 && wb + 0 < W) ? row[wb + 0] : 0.f;
            v.y = (wb + 1 >= 0 && wb + 1 < W) ? row[wb + 1] : 0.f;
            v.z = (wb + 2 >= 0 && wb + 2 < W) ? row[wb + 2] : 0.f;
            v.w = (wb + 3 >= 0 && wb + 3 < W) ? row[wb + 3] : 0.f;
        }
        span[4 * k + 0] = v.x;
        span[4 * k + 1] = v.y;
        span[4 * k + 2] = v.z;
        span[4 * k + 3] = v.w;
    }

    // residual: x itself (span center)
    float acc0 = span[HALO + 0];
    float acc1 = span[HALO + 1];
    float acc2 = span[HALO + 2];
    float acc3 = span[HALO + 3];

    // --- horizontal stencil (static register indexing) ---
#pragma unroll
    for (int d = 0; d < NW; ++d) {
        const float wg = wth[d];
        acc0 = fmaf(wg, span[d + 0], acc0);
        acc1 = fmaf(wg, span[d + 1], acc1);
        acc2 = fmaf(wg, span[d + 2], acc2);
        acc3 = fmaf(wg, span[d + 3], acc3);
    }

    // --- vertical stencil (coalesced float4 row loads, uniform skip) ---
#pragma unroll
    for (int d = 0; d < NW; ++d) {
        const float wg = wtv[d];
        const int hh = h + d - HALO;
        if (wg != 0.f && hh >= 0 && hh < H) {
            const float4 v = *(const float4*)(plane + (size_t)hh * W + w0);
            acc0 = fmaf(wg, v.x, acc0);
            acc1 = fmaf(wg, v.y, acc1);
            acc2 = fmaf(wg, v.z, acc2);
            acc3 = fmaf(wg, v.w, acc3);
        }
    }

    float4 o;
    o.x = acc0; o.y = acc1; o.z = acc2; o.w = acc3;
    *(float4*)(out + (size_t)bc * H * W + (size_t)h * W + w0) = o;
}

extern "C" void kernel_launch(void* const* d_in, const int* in_sizes, int n_in,
                              void* d_out, int out_size, void* d_ws, size_t ws_size,
                              hipStream_t stream) {
    const float* x  = (const float*)d_in[0];
    const float* wh = (const float*)d_in[1];
    const float* ww = (const float*)d_in[2];
    const float* rp = (const float*)d_in[3];
    float* out = (float*)d_out;
    float* ws  = (float*)d_ws;

    build_stencils<<<C, 64, 0, stream>>>(wh, ww, rp, ws);
    const int blocks = B * C * (H / 4);   // 49152
    axialdw_kernel<<<blocks, 256, 0, stream>>>(x, ws, out);
}